// Round 5
// baseline (142.946 us; speedup 1.0000x reference)
//
#include <hip/hip_runtime.h>

#define NB 32
#define WAVES_PER_BLOCK 4

__device__ __forceinline__ float clamp01(float x) {
    return fminf(fmaxf(x, 0.0f), 1.0f);
}

// One 64-lane wave per (b,s) token; 4 tokens per 256-thread block.
// Register layout: lane (i = lw&31, half = lw>>5) owns the ROW-SLICE
// W[i][half*16 .. half*16+15] in wrow[4]. Pass 1 (inflow) consumes W
// straight from registers; the two halves' partial sums merge with one
// __shfl_xor(32) set. Pass 2 reuses the same registers for the W update
// and h_new[i] is already in-register. LDS holds only the h / h_new
// broadcast buffers (4 KB/block); all LDS is wave-private -> no
// __syncthreads, waves run decoupled. launch_bounds(256,8) -> 32 waves/CU.
__global__ __launch_bounds__(256, 8) void biotoken_step(
    const float* __restrict__ h,
    const float* __restrict__ W,
    const float* __restrict__ stim,
    float* __restrict__ out_h,
    float* __restrict__ out_W)
{
    const int lw    = threadIdx.x & 63;   // lane in wave
    const int wave  = threadIdx.x >> 6;   // 0..3
    const int token = blockIdx.x * WAVES_PER_BLOCK + wave;
    const int i     = lw & 31;            // row this lane owns
    const int half  = lw >> 5;            // column-half this lane owns
    const int c0    = half * 16;          // first owned column

    __shared__ float s_hin [WAVES_PER_BLOCK][NB * 4];
    __shared__ float s_hnew[WAVES_PER_BLOCK][NB * 4];

    // ---- stage: W row-slice -> registers; h -> LDS; stim -> register ----
    const float*  Wt  = W + (size_t)token * (NB * NB);
    const float4* wrp = (const float4*)(Wt + i * NB + c0);
    float4 wrow[4];
    wrow[0] = wrp[0];
    wrow[1] = wrp[1];
    wrow[2] = wrp[2];
    wrow[3] = wrp[3];

    if (lw < NB) {
        ((float4*)s_hin[wave])[lw] =
            ((const float4*)(h + (size_t)token * (NB * 4)))[lw];
    }
    const float sti = stim[(size_t)token * NB + i];
    __builtin_amdgcn_wave_barrier();      // scheduling fence only

    const float* shin = s_hin[wave];
    const float* wf   = (const float*)wrow;   // static-indexed below (unrolled)

    // ---- pass 1: inflow over this lane's 16 owned columns ----
    float accE = 0.f, accP = 0.f, accG = 0.f, accL = 0.f, tot = 0.f;
    #pragma unroll
    for (int t = 0; t < 16; ++t) {
        const int j = c0 + t;
        float w = wf[t];                       // W[i][j], compile-time index
        w = (j == i) ? 0.0f : w;               // zero self-connection
        const float4 hj = *(const float4*)&shin[j * 4];   // broadcast read
        accE = fmaf(w, hj.x, accE);
        accP = fmaf(w, hj.y, accP);
        accG = fmaf(w, hj.z, accG);
        accL = fmaf(w, hj.w, accL);
        tot += w;
    }
    // merge the two column-halves of row i
    accE += __shfl_xor(accE, 32);
    accP += __shfl_xor(accP, 32);
    accG += __shfl_xor(accG, 32);
    accL += __shfl_xor(accL, 32);
    tot  += __shfl_xor(tot,  32);

    const float inv = 1.0f / (tot + 1e-8f);
    const float En = accE * inv, Pn = accP * inv, Gn = accG * inv, Ln = accL * inv;

    // ---- EPGL state update for row i (redundant across halves) ----
    const float4 hi = *(const float4*)&shin[i * 4];
    const float E = hi.x, P = hi.y, G = hi.z, L = hi.w;

    const float E_new = clamp01(E + 0.3f * sti - 0.4f * P - 0.2f * G);
    const float P_new = clamp01(P + 0.5f * sti + 0.3f * (Pn - P) - 0.2f * E);
    const float G_new = clamp01(G + 0.4f * E * (1.0f - P) + 0.2f * (Gn - G) - 0.3f * P);
    const float good  = 0.5f * En + 0.5f * Gn;
    const float L_new = clamp01(L + 0.4f * good + 0.3f * (Ln - L) - 0.3f * P);

    const float4 hr = make_float4(E_new, P_new, G_new, L_new);  // h_new[i], in-register
    if (half == 0) {
        ((float4*)s_hnew[wave])[i] = hr;
        ((float4*)(out_h + (size_t)token * (NB * 4)))[i] = hr;
    }
    __builtin_amdgcn_wave_barrier();      // scheduling fence only

    // ---- pass 2: W_new for the lane's 16 owned (i, j) entries ----
    const float* shn = s_hnew[wave];
    const float  Lr  = hr.w;
    float4* outWr = (float4*)(out_W + (size_t)token * (NB * NB) + i * NB + c0);

    #pragma unroll
    for (int e = 0; e < 4; ++e) {
        float4 res;
        float* resp = &res.x;
        #pragma unroll
        for (int q = 0; q < 4; ++q) {
            const int t = 4 * e + q;
            const int j = c0 + t;
            const float4 hj = *(const float4*)&shn[j * 4];  // broadcast read
            const float dx = hr.x - hj.x;
            const float dy = hr.y - hj.y;
            const float dz = hr.z - hj.z;
            const float dw = hr.w - hj.w;
            const float sq = dx * dx + dy * dy + dz * dz + dw * dw;
            const float dist = sqrtf(sq);                   // sqrt(0)=0 matches ref
            const float mutual = 0.5f * (Lr + hj.w);
            float wn = 0.95f * wf[t] + 0.1f * mutual * dist;
            wn = clamp01(wn);
            resp[q] = (j == i) ? 0.0f : wn;                 // zero diagonal
        }
        outWr[e] = res;
    }
}

extern "C" void kernel_launch(void* const* d_in, const int* in_sizes, int n_in,
                              void* d_out, int out_size, void* d_ws, size_t ws_size,
                              hipStream_t stream) {
    const float* h    = (const float*)d_in[0];  // [8,2048,32,4]
    const float* W    = (const float*)d_in[1];  // [8,2048,32,32]
    const float* stim = (const float*)d_in[2];  // [8,2048,32]

    const int tokens = in_sizes[2] / NB;        // 16384
    float* out_h = (float*)d_out;               // [8,2048,32,4]
    float* out_W = (float*)d_out + (size_t)tokens * NB * 4;  // [8,2048,32,32]

    const int blocks = tokens / WAVES_PER_BLOCK; // 4096
    biotoken_step<<<blocks, 256, 0, stream>>>(h, W, stim, out_h, out_W);
}